// Round 1
// baseline (297.140 us; speedup 1.0000x reference)
//
#include <hip/hip_runtime.h>

// Causal MHA forward, B=2 T=2048 C=1024 H=16 hs=64, fp32 in/out, bf16 MFMA internally.
// Pipeline: conv x -> bf16 | transpose-conv W -> bf16 NxK | GEMM1 (epilogue scatters Q,K,V
// into per-head layouts, V transposed) | flash attention (online softmax, exp2 domain) |
// GEMM2 (+bias, fp32 out).

typedef unsigned short u16;
typedef unsigned int u32;
typedef __bf16 bf16x8 __attribute__((ext_vector_type(8)));
typedef float f32x4 __attribute__((ext_vector_type(4)));
typedef u32 u32x4 __attribute__((ext_vector_type(4)));
typedef u16 u16x4 __attribute__((ext_vector_type(4)));

__device__ __forceinline__ u16 f2bf(float f) {
  u32 u = __float_as_uint(f);
  u32 r = u + 0x7FFFu + ((u >> 16) & 1u);  // round-to-nearest-even, finite inputs only
  return (u16)(r >> 16);
}

__device__ __forceinline__ bf16x8 ld_bf8(const u16* p) {
  union { u32x4 u; bf16x8 b; } x;
  x.u = *(const u32x4*)p;
  return x.b;
}

// ---- fp32 -> bf16, 8 elements/thread, 4M elements total ----
__global__ __launch_bounds__(256) void conv_x_kernel(const float* __restrict__ src,
                                                     u16* __restrict__ dst) {
  int idx = blockIdx.x * 256 + threadIdx.x;
  const float4* s4 = (const float4*)src;
  float4 a = s4[2 * idx], b = s4[2 * idx + 1];
  union { u16 h[8]; u32x4 v; } pk;
  pk.h[0] = f2bf(a.x); pk.h[1] = f2bf(a.y); pk.h[2] = f2bf(a.z); pk.h[3] = f2bf(a.w);
  pk.h[4] = f2bf(b.x); pk.h[5] = f2bf(b.y); pk.h[6] = f2bf(b.z); pk.h[7] = f2bf(b.w);
  *(u32x4*)&dst[(size_t)idx * 8] = pk.v;
}

// ---- fp32 (R x Cc) -> bf16 transposed (Cc x R), 64x64 LDS tiles ----
__global__ __launch_bounds__(256) void convT_kernel(const float* __restrict__ src,
                                                    u16* __restrict__ dst, int R, int Cc) {
  __shared__ float ls[64][65];
  int r0 = blockIdx.x * 64, c0 = blockIdx.y * 64;
  int t = threadIdx.x;
  for (int u = t; u < 1024; u += 256) {
    int r = u >> 4, cs = (u & 15) << 2;
    float4 v = *(const float4*)&src[(size_t)(r0 + r) * Cc + (c0 + cs)];
    ls[r][cs] = v.x; ls[r][cs + 1] = v.y; ls[r][cs + 2] = v.z; ls[r][cs + 3] = v.w;
  }
  __syncthreads();
  for (int u = t; u < 1024; u += 256) {
    int n = u >> 4, ks = (u & 15) << 2;
    u16x4 o;
    o.x = f2bf(ls[ks][n]); o.y = f2bf(ls[ks + 1][n]);
    o.z = f2bf(ls[ks + 2][n]); o.w = f2bf(ls[ks + 3][n]);
    *(u16x4*)&dst[(size_t)(c0 + n) * R + (r0 + ks)] = o;
  }
}

// ---- bf16 GEMM: C(MxN) = A(MxK,row) @ Bt(NxK,row)^T, K=1024, tile 128x128, BK=32 ----
// mode 0: scatter into Qh[bh][t][d] (scaled), Kh[bh][t][d], Vt[bh][d][t]
// mode 1: out[row][col] = acc + bias[col] (fp32)
__global__ __launch_bounds__(256) void gemm_bt_kernel(
    const u16* __restrict__ A, const u16* __restrict__ Bt, int mode,
    u16* __restrict__ Qh, u16* __restrict__ Kh, u16* __restrict__ Vt,
    float* __restrict__ out, const float* __restrict__ bias, float qscale) {
  constexpr int K = 1024, LDT = 40;  // pad 32->40: 80B rows, 16B-aligned, 2-way banks (free)
  __shared__ __align__(16) u16 As[128 * LDT];
  __shared__ __align__(16) u16 Bs[128 * LDT];
  int t = threadIdx.x;
  int wave = t >> 6, lane = t & 63, quad = lane >> 4, l16 = lane & 15;
  int wm = (wave >> 1) << 6, wn = (wave & 1) << 6;
  int m0 = blockIdx.x * 128, n0 = blockIdx.y * 128;
  f32x4 acc[4][4] = {};
  int r1 = t >> 2, s1 = (t & 3) << 3;  // staging unit: 512 units of 16B, 2/thread
  int r2 = r1 + 64;
  for (int k0 = 0; k0 < K; k0 += 32) {
    const u16* Ag = &A[(size_t)m0 * K + k0];
    const u16* Bg = &Bt[(size_t)n0 * K + k0];
    *(u32x4*)&As[r1 * LDT + s1] = *(const u32x4*)&Ag[(size_t)r1 * K + s1];
    *(u32x4*)&As[r2 * LDT + s1] = *(const u32x4*)&Ag[(size_t)r2 * K + s1];
    *(u32x4*)&Bs[r1 * LDT + s1] = *(const u32x4*)&Bg[(size_t)r1 * K + s1];
    *(u32x4*)&Bs[r2 * LDT + s1] = *(const u32x4*)&Bg[(size_t)r2 * K + s1];
    __syncthreads();
    bf16x8 af[4], bfr[4];
    for (int r = 0; r < 4; ++r) af[r] = ld_bf8(&As[(wm + r * 16 + l16) * LDT + quad * 8]);
    for (int c = 0; c < 4; ++c) bfr[c] = ld_bf8(&Bs[(wn + c * 16 + l16) * LDT + quad * 8]);
    for (int r = 0; r < 4; ++r)
      for (int c = 0; c < 4; ++c)
        acc[r][c] = __builtin_amdgcn_mfma_f32_16x16x32_bf16(af[r], bfr[c], acc[r][c], 0, 0, 0);
    __syncthreads();
  }
  if (mode == 0) {
    for (int r = 0; r < 4; ++r) {
      int rowbase = m0 + wm + r * 16 + quad * 4;
      for (int c = 0; c < 4; ++c) {
        int col = n0 + wn + c * 16 + l16;
        int seg = col >> 10;
        int cc = col & 1023;
        int h = cc >> 6, d = cc & 63;
        for (int i = 0; i < 4; ++i) {
          int row = rowbase + i;
          int b = row >> 11, tt = row & 2047;
          int bh = b * 16 + h;
          float v = acc[r][c][i];
          if (seg == 0)      Qh[((size_t)bh * 2048 + tt) * 64 + d] = f2bf(v * qscale);
          else if (seg == 1) Kh[((size_t)bh * 2048 + tt) * 64 + d] = f2bf(v);
          else               Vt[((size_t)bh * 64 + d) * 2048 + tt] = f2bf(v);
        }
      }
    }
  } else {
    for (int r = 0; r < 4; ++r) {
      int rowbase = m0 + wm + r * 16 + quad * 4;
      for (int c = 0; c < 4; ++c) {
        int col = n0 + wn + c * 16 + l16;
        float bv = bias[col];
        for (int i = 0; i < 4; ++i)
          out[(size_t)(rowbase + i) * 1024 + col] = acc[r][c][i] + bv;
      }
    }
  }
}

// ---- flash attention: BQ=BN=64, 4 waves x 16 q-rows, online softmax in exp2 domain ----
__global__ __launch_bounds__(256) void flash_kernel(
    const u16* __restrict__ Qh, const u16* __restrict__ Kh, const u16* __restrict__ Vt,
    u16* __restrict__ yb) {
  constexpr int LDK = 72;  // 144B rows: 16B-aligned, 2-way banks (free)
  __shared__ __align__(16) u16 Ks[64 * LDK];
  __shared__ __align__(16) u16 Vs[64 * LDK];
  __shared__ __align__(16) u16 Ps[64 * LDK];
  int t = threadIdx.x, wave = t >> 6, lane = t & 63, quad = lane >> 4, l16 = lane & 15;
  int qtile = 31 - blockIdx.x;  // long blocks first
  int bh = blockIdx.y;
  int q0 = qtile << 6;
  const u16* Qb = Qh + (size_t)bh * 2048 * 64;
  const u16* Kb = Kh + (size_t)bh * 2048 * 64;
  const u16* Vb = Vt + (size_t)bh * 64 * 2048;
  bf16x8 qa0, qa1;
  {
    int qrow = q0 + wave * 16 + l16;  // A-operand: m = lane&15
    qa0 = ld_bf8(&Qb[(size_t)qrow * 64 + quad * 8]);
    qa1 = ld_bf8(&Qb[(size_t)qrow * 64 + 32 + quad * 8]);
  }
  f32x4 oacc[4] = {};
  float mrow[4], lrow[4];
  for (int i = 0; i < 4; ++i) { mrow[i] = -1e30f; lrow[i] = 0.f; }
  int nkv = qtile + 1;
  int r1 = t >> 3, s1 = (t & 7) << 3, r2 = r1 + 32;  // 512 staging units of 16B
  for (int j = 0; j < nkv; ++j) {
    int kv0 = j << 6;
    *(u32x4*)&Ks[r1 * LDK + s1] = *(const u32x4*)&Kb[(size_t)(kv0 + r1) * 64 + s1];
    *(u32x4*)&Ks[r2 * LDK + s1] = *(const u32x4*)&Kb[(size_t)(kv0 + r2) * 64 + s1];
    *(u32x4*)&Vs[r1 * LDK + s1] = *(const u32x4*)&Vb[(size_t)r1 * 2048 + kv0 + s1];
    *(u32x4*)&Vs[r2 * LDK + s1] = *(const u32x4*)&Vb[(size_t)r2 * 2048 + kv0 + s1];
    __syncthreads();
    f32x4 s[4];
    for (int c = 0; c < 4; ++c) {
      bf16x8 kb0 = ld_bf8(&Ks[(c * 16 + l16) * LDK + quad * 8]);
      bf16x8 kb1 = ld_bf8(&Ks[(c * 16 + l16) * LDK + 32 + quad * 8]);
      f32x4 z = {0.f, 0.f, 0.f, 0.f};
      z = __builtin_amdgcn_mfma_f32_16x16x32_bf16(qa0, kb0, z, 0, 0, 0);
      s[c] = __builtin_amdgcn_mfma_f32_16x16x32_bf16(qa1, kb1, z, 0, 0, 0);
    }
    if (j == nkv - 1) {  // diagonal tile: mask t > q (kv0 == q0 here)
      for (int c = 0; c < 4; ++c)
        for (int i = 0; i < 4; ++i) {
          int qq = wave * 16 + quad * 4 + i;
          int tk = c * 16 + l16;
          if (tk > qq) s[c][i] = -1e30f;
        }
    }
    float alpha[4];
    for (int i = 0; i < 4; ++i) {
      float v = fmaxf(fmaxf(s[0][i], s[1][i]), fmaxf(s[2][i], s[3][i]));
      v = fmaxf(v, __shfl_xor(v, 1));
      v = fmaxf(v, __shfl_xor(v, 2));
      v = fmaxf(v, __shfl_xor(v, 4));
      v = fmaxf(v, __shfl_xor(v, 8));
      float mnew = fmaxf(mrow[i], v);
      alpha[i] = exp2f(mrow[i] - mnew);
      mrow[i] = mnew;
    }
    float rsum[4] = {0.f, 0.f, 0.f, 0.f};
    for (int c = 0; c < 4; ++c)
      for (int i = 0; i < 4; ++i) {
        float p = exp2f(s[c][i] - mrow[i]);
        rsum[i] += p;
        // C-layout -> LDS (row = quad*4+i, col = c*16+l16), per-wave strip, no barrier needed
        Ps[(wave * 16 + quad * 4 + i) * LDK + c * 16 + l16] = f2bf(p);
      }
    for (int i = 0; i < 4; ++i) {
      float v = rsum[i];
      v += __shfl_xor(v, 1); v += __shfl_xor(v, 2);
      v += __shfl_xor(v, 4); v += __shfl_xor(v, 8);
      lrow[i] = lrow[i] * alpha[i] + v;
    }
    for (int dt = 0; dt < 4; ++dt)
      for (int i = 0; i < 4; ++i) oacc[dt][i] *= alpha[i];
    bf16x8 pa0 = ld_bf8(&Ps[(wave * 16 + l16) * LDK + quad * 8]);       // A-layout readback
    bf16x8 pa1 = ld_bf8(&Ps[(wave * 16 + l16) * LDK + 32 + quad * 8]);
    for (int dt = 0; dt < 4; ++dt) {
      bf16x8 vb0 = ld_bf8(&Vs[(dt * 16 + l16) * LDK + quad * 8]);
      bf16x8 vb1 = ld_bf8(&Vs[(dt * 16 + l16) * LDK + 32 + quad * 8]);
      oacc[dt] = __builtin_amdgcn_mfma_f32_16x16x32_bf16(pa0, vb0, oacc[dt], 0, 0, 0);
      oacc[dt] = __builtin_amdgcn_mfma_f32_16x16x32_bf16(pa1, vb1, oacc[dt], 0, 0, 0);
    }
    __syncthreads();
  }
  int b = bh >> 4, h = bh & 15;
  for (int i = 0; i < 4; ++i) {
    float inv = 1.0f / lrow[i];
    int qq = q0 + wave * 16 + quad * 4 + i;
    size_t rowoff = ((size_t)(b * 2048 + qq)) * 1024 + h * 64;
    for (int dt = 0; dt < 4; ++dt)
      yb[rowoff + dt * 16 + l16] = f2bf(oacc[dt][i] * inv);
  }
}

extern "C" void kernel_launch(void* const* d_in, const int* in_sizes, int n_in,
                              void* d_out, int out_size, void* d_ws, size_t ws_size,
                              hipStream_t stream) {
  const float* x     = (const float*)d_in[0];
  const float* Wkqv  = (const float*)d_in[1];
  const float* Wproj = (const float*)d_in[2];
  const float* bproj = (const float*)d_in[3];
  float* out = (float*)d_out;

  u16* ws     = (u16*)d_ws;                       // 48 MB total scratch
  u16* xb     = ws;                               // 4096x1024 bf16
  u16* wkqvT  = xb + (size_t)4096 * 1024;         // 3072x1024 bf16 (W_kqv^T)
  u16* wprojT = wkqvT + (size_t)3072 * 1024;      // 1024x1024 bf16 (W_proj^T)
  u16* Qh     = wprojT + (size_t)1024 * 1024;     // [32][2048][64] bf16, pre-scaled
  u16* Kh     = Qh + (size_t)32 * 2048 * 64;      // [32][2048][64]
  u16* Vt     = Kh + (size_t)32 * 2048 * 64;      // [32][64][2048] (transposed)
  u16* yb     = Vt + (size_t)32 * 2048 * 64;      // 4096x1024 bf16 attention output

  const float QSCALE = 0.18033688011112042f;  // (1/sqrt(64)) * log2(e), exp2-domain softmax

  conv_x_kernel<<<2048, 256, 0, stream>>>(x, xb);
  convT_kernel<<<dim3(16, 48), 256, 0, stream>>>(Wkqv, wkqvT, 1024, 3072);
  convT_kernel<<<dim3(16, 16), 256, 0, stream>>>(Wproj, wprojT, 1024, 1024);
  gemm_bt_kernel<<<dim3(32, 24), 256, 0, stream>>>(xb, wkqvT, 0, Qh, Kh, Vt,
                                                   nullptr, nullptr, QSCALE);
  flash_kernel<<<dim3(32, 32), 256, 0, stream>>>(Qh, Kh, Vt, yb);
  gemm_bt_kernel<<<dim3(32, 8), 256, 0, stream>>>(yb, wprojT, 1, nullptr, nullptr, nullptr,
                                                  out, bproj, 1.0f);
}

// Round 2
// 238.188 us; speedup vs baseline: 1.2475x; 1.2475x over previous
//
#include <hip/hip_runtime.h>

// Causal MHA forward, B=2 T=2048 C=1024 H=16 hs=64, fp32 in/out, bf16 MFMA internally.
// R2: flash uses static-max exp2 softmax (no shuffle reductions, rowsum via ones-frag mfma),
// VGPR-pipelined K/V staging; GEMMs use global_load_lds width-16 + XOR-swizzled LDS.

typedef unsigned short u16;
typedef unsigned int u32;
typedef __bf16 bf16x8 __attribute__((ext_vector_type(8)));
typedef float f32x4 __attribute__((ext_vector_type(4)));
typedef u32 u32x4 __attribute__((ext_vector_type(4)));
typedef u16 u16x4 __attribute__((ext_vector_type(4)));

__device__ __forceinline__ u16 f2bf(float f) {
  u32 u = __float_as_uint(f);
  u32 r = u + 0x7FFFu + ((u >> 16) & 1u);  // RNE, finite inputs only
  return (u16)(r >> 16);
}

__device__ __forceinline__ bf16x8 ld_bf8(const u16* p) {
  union { u32x4 u; bf16x8 b; } x;
  x.u = *(const u32x4*)p;
  return x.b;
}

// async global -> LDS, 16B per lane (HW: wave-uniform base + lane*16)
__device__ __forceinline__ void gld_lds16(const u16* g, u16* l) {
  __builtin_amdgcn_global_load_lds(
      (const __attribute__((address_space(1))) u32*)g,
      (__attribute__((address_space(3))) u32*)l, 16, 0, 0);
}

// ---- fp32 -> bf16, 8 elements/thread ----
__global__ __launch_bounds__(256) void conv_x_kernel(const float* __restrict__ src,
                                                     u16* __restrict__ dst) {
  int idx = blockIdx.x * 256 + threadIdx.x;
  const float4* s4 = (const float4*)src;
  float4 a = s4[2 * idx], b = s4[2 * idx + 1];
  union { u16 h[8]; u32x4 v; } pk;
  pk.h[0] = f2bf(a.x); pk.h[1] = f2bf(a.y); pk.h[2] = f2bf(a.z); pk.h[3] = f2bf(a.w);
  pk.h[4] = f2bf(b.x); pk.h[5] = f2bf(b.y); pk.h[6] = f2bf(b.z); pk.h[7] = f2bf(b.w);
  *(u32x4*)&dst[(size_t)idx * 8] = pk.v;
}

// ---- fp32 (R x Cc) -> bf16 transposed (Cc x R), 64x64 LDS tiles ----
__global__ __launch_bounds__(256) void convT_kernel(const float* __restrict__ src,
                                                    u16* __restrict__ dst, int R, int Cc) {
  __shared__ float ls[64][65];
  int r0 = blockIdx.x * 64, c0 = blockIdx.y * 64;
  int t = threadIdx.x;
  for (int u = t; u < 1024; u += 256) {
    int r = u >> 4, cs = (u & 15) << 2;
    float4 v = *(const float4*)&src[(size_t)(r0 + r) * Cc + (c0 + cs)];
    ls[r][cs] = v.x; ls[r][cs + 1] = v.y; ls[r][cs + 2] = v.z; ls[r][cs + 3] = v.w;
  }
  __syncthreads();
  for (int u = t; u < 1024; u += 256) {
    int n = u >> 4, ks = (u & 15) << 2;
    u16x4 o;
    o.x = f2bf(ls[ks][n]); o.y = f2bf(ls[ks + 1][n]);
    o.z = f2bf(ls[ks + 2][n]); o.w = f2bf(ls[ks + 3][n]);
    *(u16x4*)&dst[(size_t)(c0 + n) * R + (r0 + ks)] = o;
  }
}

// ---- bf16 GEMM: C(MxN) = A(MxK,row) @ Bt(NxK,row)^T, K=1024, tile 128x128, BK=32 ----
// global_load_lds staging, LDT=32 with XOR swizzle (colblock ^= (row>>1)&3) -> 2-way reads.
// mode 0: scatter Qh (scaled), Kh, Vt(transposed). mode 1: out = acc + bias (fp32).
__global__ __launch_bounds__(256) void gemm_bt_kernel(
    const u16* __restrict__ A, const u16* __restrict__ Bt, int mode,
    u16* __restrict__ Qh, u16* __restrict__ Kh, u16* __restrict__ Vt,
    float* __restrict__ out, const float* __restrict__ bias, float qscale) {
  constexpr int K = 1024;
  __shared__ __align__(16) u16 As[128 * 32];
  __shared__ __align__(16) u16 Bs[128 * 32];
  int t = threadIdx.x;
  int wave = t >> 6, lane = t & 63, quad = lane >> 4, l16 = lane & 15;
  int wm = (wave >> 1) << 6, wn = (wave & 1) << 6;
  int m0 = blockIdx.x * 128, n0 = blockIdx.y * 128;
  f32x4 acc[4][4] = {};
  // staging units: 512 of 16B per matrix; wave w owns units [w*128, w*128+128)
  int u0 = wave * 128 + lane, u1 = u0 + 64;
  int ra0 = u0 >> 2, ca0 = ((u0 & 3) ^ ((u0 >> 3) & 3)) << 3;
  int ra1 = u1 >> 2, ca1 = ((u1 & 3) ^ ((u1 >> 3) & 3)) << 3;
  int swq = (quad ^ ((l16 >> 1) & 3)) << 3;  // read-side swizzled col (row base mult of 16)
  for (int k0 = 0; k0 < K; k0 += 32) {
    const u16* Ag = &A[(size_t)m0 * K + k0];
    const u16* Bg = &Bt[(size_t)n0 * K + k0];
    gld_lds16(&Ag[(size_t)ra0 * K + ca0], &As[u0 * 8]);
    gld_lds16(&Ag[(size_t)ra1 * K + ca1], &As[u1 * 8]);
    gld_lds16(&Bg[(size_t)ra0 * K + ca0], &Bs[u0 * 8]);
    gld_lds16(&Bg[(size_t)ra1 * K + ca1], &Bs[u1 * 8]);
    __syncthreads();
    bf16x8 af[4], bfr[4];
    for (int r = 0; r < 4; ++r) af[r] = ld_bf8(&As[(wm + r * 16 + l16) * 32 + swq]);
    for (int c = 0; c < 4; ++c) bfr[c] = ld_bf8(&Bs[(wn + c * 16 + l16) * 32 + swq]);
    for (int r = 0; r < 4; ++r)
      for (int c = 0; c < 4; ++c)
        acc[r][c] = __builtin_amdgcn_mfma_f32_16x16x32_bf16(af[r], bfr[c], acc[r][c], 0, 0, 0);
    __syncthreads();
  }
  if (mode == 0) {
    for (int r = 0; r < 4; ++r) {
      int rowbase = m0 + wm + r * 16 + quad * 4;
      for (int c = 0; c < 4; ++c) {
        int col = n0 + wn + c * 16 + l16;
        int seg = col >> 10;
        int cc = col & 1023;
        int h = cc >> 6, d = cc & 63;
        for (int i = 0; i < 4; ++i) {
          int row = rowbase + i;
          int b = row >> 11, tt = row & 2047;
          int bh = b * 16 + h;
          float v = acc[r][c][i];
          if (seg == 0)      Qh[((size_t)bh * 2048 + tt) * 64 + d] = f2bf(v * qscale);
          else if (seg == 1) Kh[((size_t)bh * 2048 + tt) * 64 + d] = f2bf(v);
          else               Vt[((size_t)bh * 64 + d) * 2048 + tt] = f2bf(v);
        }
      }
    }
  } else {
    for (int r = 0; r < 4; ++r) {
      int rowbase = m0 + wm + r * 16 + quad * 4;
      for (int c = 0; c < 4; ++c) {
        int col = n0 + wn + c * 16 + l16;
        float bv = bias[col];
        for (int i = 0; i < 4; ++i)
          out[(size_t)(rowbase + i) * 1024 + col] = acc[r][c][i] + bv;
      }
    }
  }
}

// ---- flash attention: BQ=BN=64, 4 waves x 16 q-rows ----
// static-max exp2 softmax (scores pre-scaled by log2e/8); rowsum via ones-frag mfma;
// K/V staging software-pipelined through VGPRs.
__global__ __launch_bounds__(256) void flash_kernel(
    const u16* __restrict__ Qh, const u16* __restrict__ Kh, const u16* __restrict__ Vt,
    u16* __restrict__ yb) {
  constexpr int LDK = 72;  // 144B rows: 16B-aligned, frag reads 2-way (free)
  __shared__ __align__(16) u16 Ks[64 * LDK];
  __shared__ __align__(16) u16 Vs[64 * LDK];
  __shared__ __align__(16) u16 Ps[64 * LDK];
  int t = threadIdx.x, wave = t >> 6, lane = t & 63, quad = lane >> 4, l16 = lane & 15;
  int qtile = 31 - blockIdx.x;  // long blocks first
  int bh = blockIdx.y;
  int q0 = qtile << 6;
  const u16* Qb = Qh + (size_t)bh * 2048 * 64;
  const u16* Kb = Kh + (size_t)bh * 2048 * 64;
  const u16* Vb = Vt + (size_t)bh * 64 * 2048;
  bf16x8 qa0, qa1;
  {
    int qrow = q0 + wave * 16 + l16;  // A-operand: m = lane&15
    qa0 = ld_bf8(&Qb[(size_t)qrow * 64 + quad * 8]);
    qa1 = ld_bf8(&Qb[(size_t)qrow * 64 + 32 + quad * 8]);
  }
  bf16x8 onesf;  // B-frag: column n=0 all ones -> D[:,0] = rowsum
  {
    union { u16 h[8]; bf16x8 b; } o;
    u16 v = (l16 == 0) ? (u16)0x3F80 : (u16)0;
    for (int i = 0; i < 8; ++i) o.h[i] = v;
    onesf = o.b;
  }
  f32x4 oacc[4] = {};
  f32x4 lacc = {};
  int nkv = qtile + 1;
  int r1 = t >> 3, s1 = (t & 7) << 3, r2 = r1 + 32;  // 512 staging units of 16B
  u32x4 kreg0, kreg1, vreg0, vreg1;
  kreg0 = *(const u32x4*)&Kb[(size_t)r1 * 64 + s1];
  kreg1 = *(const u32x4*)&Kb[(size_t)r2 * 64 + s1];
  vreg0 = *(const u32x4*)&Vb[(size_t)r1 * 2048 + s1];
  vreg1 = *(const u32x4*)&Vb[(size_t)r2 * 2048 + s1];
  for (int j = 0; j < nkv; ++j) {
    __syncthreads();  // all waves done reading previous tile
    *(u32x4*)&Ks[r1 * LDK + s1] = kreg0;
    *(u32x4*)&Ks[r2 * LDK + s1] = kreg1;
    *(u32x4*)&Vs[r1 * LDK + s1] = vreg0;
    *(u32x4*)&Vs[r2 * LDK + s1] = vreg1;
    __syncthreads();
    if (j + 1 < nkv) {  // prefetch next tile into regs; overlaps with compute below
      int kv0 = (j + 1) << 6;
      kreg0 = *(const u32x4*)&Kb[(size_t)(kv0 + r1) * 64 + s1];
      kreg1 = *(const u32x4*)&Kb[(size_t)(kv0 + r2) * 64 + s1];
      vreg0 = *(const u32x4*)&Vb[(size_t)r1 * 2048 + kv0 + s1];
      vreg1 = *(const u32x4*)&Vb[(size_t)r2 * 2048 + kv0 + s1];
    }
    f32x4 s[4];
    for (int c = 0; c < 4; ++c) {
      bf16x8 kb0 = ld_bf8(&Ks[(c * 16 + l16) * LDK + quad * 8]);
      bf16x8 kb1 = ld_bf8(&Ks[(c * 16 + l16) * LDK + 32 + quad * 8]);
      f32x4 z = {0.f, 0.f, 0.f, 0.f};
      z = __builtin_amdgcn_mfma_f32_16x16x32_bf16(qa0, kb0, z, 0, 0, 0);
      s[c] = __builtin_amdgcn_mfma_f32_16x16x32_bf16(qa1, kb1, z, 0, 0, 0);
    }
    bool diag = (j == nkv - 1);
    for (int c = 0; c < 4; ++c)
      for (int i = 0; i < 4; ++i) {
        float p = __builtin_amdgcn_exp2f(s[c][i]);
        if (diag && (c * 16 + l16 > wave * 16 + quad * 4 + i)) p = 0.f;
        // C-layout -> LDS A-layout strip (per-wave rows, no barrier needed)
        Ps[(wave * 16 + quad * 4 + i) * LDK + c * 16 + l16] = f2bf(p);
      }
    bf16x8 pa0 = ld_bf8(&Ps[(wave * 16 + l16) * LDK + quad * 8]);
    bf16x8 pa1 = ld_bf8(&Ps[(wave * 16 + l16) * LDK + 32 + quad * 8]);
    lacc = __builtin_amdgcn_mfma_f32_16x16x32_bf16(pa0, onesf, lacc, 0, 0, 0);
    lacc = __builtin_amdgcn_mfma_f32_16x16x32_bf16(pa1, onesf, lacc, 0, 0, 0);
    for (int dt = 0; dt < 4; ++dt) {
      bf16x8 vb0 = ld_bf8(&Vs[(dt * 16 + l16) * LDK + quad * 8]);
      bf16x8 vb1 = ld_bf8(&Vs[(dt * 16 + l16) * LDK + 32 + quad * 8]);
      oacc[dt] = __builtin_amdgcn_mfma_f32_16x16x32_bf16(pa0, vb0, oacc[dt], 0, 0, 0);
      oacc[dt] = __builtin_amdgcn_mfma_f32_16x16x32_bf16(pa1, vb1, oacc[dt], 0, 0, 0);
    }
  }
  int b = bh >> 4, h = bh & 15;
  for (int i = 0; i < 4; ++i) {
    float l = __shfl(lacc[i], quad * 16);  // rowsum lives at col 0 (lane l16==0)
    float inv = 1.0f / l;
    int qq = q0 + wave * 16 + quad * 4 + i;
    size_t rowoff = ((size_t)(b * 2048 + qq)) * 1024 + h * 64;
    for (int dt = 0; dt < 4; ++dt)
      yb[rowoff + dt * 16 + l16] = f2bf(oacc[dt][i] * inv);
  }
}

extern "C" void kernel_launch(void* const* d_in, const int* in_sizes, int n_in,
                              void* d_out, int out_size, void* d_ws, size_t ws_size,
                              hipStream_t stream) {
  const float* x     = (const float*)d_in[0];
  const float* Wkqv  = (const float*)d_in[1];
  const float* Wproj = (const float*)d_in[2];
  const float* bproj = (const float*)d_in[3];
  float* out = (float*)d_out;

  u16* ws     = (u16*)d_ws;                       // 48 MB total scratch
  u16* xb     = ws;                               // 4096x1024 bf16
  u16* wkqvT  = xb + (size_t)4096 * 1024;         // 3072x1024 bf16 (W_kqv^T)
  u16* wprojT = wkqvT + (size_t)3072 * 1024;      // 1024x1024 bf16 (W_proj^T)
  u16* Qh     = wprojT + (size_t)1024 * 1024;     // [32][2048][64] bf16, pre-scaled
  u16* Kh     = Qh + (size_t)32 * 2048 * 64;      // [32][2048][64]
  u16* Vt     = Kh + (size_t)32 * 2048 * 64;      // [32][64][2048] (transposed)
  u16* yb     = Vt + (size_t)32 * 2048 * 64;      // 4096x1024 bf16 attention output

  const float QSCALE = 0.18033688011112042f;  // (1/sqrt(64)) * log2(e), exp2-domain softmax

  conv_x_kernel<<<2048, 256, 0, stream>>>(x, xb);
  convT_kernel<<<dim3(16, 48), 256, 0, stream>>>(Wkqv, wkqvT, 1024, 3072);
  convT_kernel<<<dim3(16, 16), 256, 0, stream>>>(Wproj, wprojT, 1024, 1024);
  gemm_bt_kernel<<<dim3(32, 24), 256, 0, stream>>>(xb, wkqvT, 0, Qh, Kh, Vt,
                                                   nullptr, nullptr, QSCALE);
  flash_kernel<<<dim3(32, 32), 256, 0, stream>>>(Qh, Kh, Vt, yb);
  gemm_bt_kernel<<<dim3(32, 8), 256, 0, stream>>>(yb, wprojT, 1, nullptr, nullptr, nullptr,
                                                  out, bproj, 1.0f);
}

// Round 3
// 203.678 us; speedup vs baseline: 1.4589x; 1.1694x over previous
//
#include <hip/hip_runtime.h>

// Causal MHA forward, B=2 T=2048 C=1024 H=16 hs=64, fp32 in/out, bf16 MFMA internally.
// R3: qkv GEMM = 128x128 tile / 8 waves (more waves/CU); V written coalesced + separate
// LDS-tile transpose; proj GEMM = 64x64 tile grid=1024 blocks (fixes 1-wave/SIMD disaster).

typedef unsigned short u16;
typedef unsigned int u32;
typedef __bf16 bf16x8 __attribute__((ext_vector_type(8)));
typedef float f32x4 __attribute__((ext_vector_type(4)));
typedef u32 u32x4 __attribute__((ext_vector_type(4)));
typedef u16 u16x4 __attribute__((ext_vector_type(4)));

__device__ __forceinline__ u16 f2bf(float f) {
  u32 u = __float_as_uint(f);
  u32 r = u + 0x7FFFu + ((u >> 16) & 1u);  // RNE, finite inputs only
  return (u16)(r >> 16);
}

__device__ __forceinline__ bf16x8 ld_bf8(const u16* p) {
  union { u32x4 u; bf16x8 b; } x;
  x.u = *(const u32x4*)p;
  return x.b;
}

__device__ __forceinline__ void gld_lds16(const u16* g, u16* l) {
  __builtin_amdgcn_global_load_lds(
      (const __attribute__((address_space(1))) u32*)g,
      (__attribute__((address_space(3))) u32*)l, 16, 0, 0);
}

// ---- fp32 -> bf16, 8 elements/thread ----
__global__ __launch_bounds__(256) void conv_x_kernel(const float* __restrict__ src,
                                                     u16* __restrict__ dst) {
  int idx = blockIdx.x * 256 + threadIdx.x;
  const float4* s4 = (const float4*)src;
  float4 a = s4[2 * idx], b = s4[2 * idx + 1];
  union { u16 h[8]; u32x4 v; } pk;
  pk.h[0] = f2bf(a.x); pk.h[1] = f2bf(a.y); pk.h[2] = f2bf(a.z); pk.h[3] = f2bf(a.w);
  pk.h[4] = f2bf(b.x); pk.h[5] = f2bf(b.y); pk.h[6] = f2bf(b.z); pk.h[7] = f2bf(b.w);
  *(u32x4*)&dst[(size_t)idx * 8] = pk.v;
}

// ---- fp32 (R x Cc) -> bf16 transposed (Cc x R), 64x64 LDS tiles ----
__global__ __launch_bounds__(256) void convT_kernel(const float* __restrict__ src,
                                                    u16* __restrict__ dst, int R, int Cc) {
  __shared__ float ls[64][65];
  int r0 = blockIdx.x * 64, c0 = blockIdx.y * 64;
  int t = threadIdx.x;
  for (int u = t; u < 1024; u += 256) {
    int r = u >> 4, cs = (u & 15) << 2;
    float4 v = *(const float4*)&src[(size_t)(r0 + r) * Cc + (c0 + cs)];
    ls[r][cs] = v.x; ls[r][cs + 1] = v.y; ls[r][cs + 2] = v.z; ls[r][cs + 3] = v.w;
  }
  __syncthreads();
  for (int u = t; u < 1024; u += 256) {
    int n = u >> 4, ks = (u & 15) << 2;
    u16x4 o;
    o.x = f2bf(ls[ks][n]); o.y = f2bf(ls[ks + 1][n]);
    o.z = f2bf(ls[ks + 2][n]); o.w = f2bf(ls[ks + 3][n]);
    *(u16x4*)&dst[(size_t)(c0 + n) * R + (r0 + ks)] = o;
  }
}

// ---- QKV GEMM: 128x128 tile, 8 waves (wave tile 32x64), BK=32, K=1024 ----
// epilogue scatters Qh (scaled), Kh, Vh -- all [bh][t][d] coalesced-ish 2B stores.
__global__ __launch_bounds__(512) void qkv_gemm_kernel(
    const u16* __restrict__ A, const u16* __restrict__ Bt,
    u16* __restrict__ Qh, u16* __restrict__ Kh, u16* __restrict__ Vh, float qscale) {
  constexpr int K = 1024;
  __shared__ __align__(16) u16 As[128 * 32];
  __shared__ __align__(16) u16 Bs[128 * 32];
  int t = threadIdx.x;
  int wave = t >> 6, lane = t & 63, quad = lane >> 4, l16 = lane & 15;
  int wm = (wave >> 1) << 5, wn = (wave & 1) << 6;  // 4x2 wave grid, wave tile 32x64
  int m0 = blockIdx.x * 128, n0 = blockIdx.y * 128;
  f32x4 acc[2][4] = {};
  int u0 = t;  // 512 units of 16B per matrix, 1 per thread per matrix
  int ra0 = u0 >> 2, ca0 = ((u0 & 3) ^ ((u0 >> 3) & 3)) << 3;  // XOR-swizzled col chunk
  int swq = (quad ^ ((l16 >> 1) & 3)) << 3;                    // read-side swizzle
  for (int k0 = 0; k0 < K; k0 += 32) {
    gld_lds16(&A[(size_t)(m0 + ra0) * K + k0 + ca0], &As[u0 * 8]);
    gld_lds16(&Bt[(size_t)(n0 + ra0) * K + k0 + ca0], &Bs[u0 * 8]);
    __syncthreads();
    bf16x8 af[2], bfr[4];
    for (int r = 0; r < 2; ++r) af[r] = ld_bf8(&As[(wm + r * 16 + l16) * 32 + swq]);
    for (int c = 0; c < 4; ++c) bfr[c] = ld_bf8(&Bs[(wn + c * 16 + l16) * 32 + swq]);
    for (int r = 0; r < 2; ++r)
      for (int c = 0; c < 4; ++c)
        acc[r][c] = __builtin_amdgcn_mfma_f32_16x16x32_bf16(af[r], bfr[c], acc[r][c], 0, 0, 0);
    __syncthreads();
  }
  for (int r = 0; r < 2; ++r) {
    int rowbase = m0 + wm + r * 16 + quad * 4;
    for (int c = 0; c < 4; ++c) {
      int col = n0 + wn + c * 16 + l16;
      int seg = col >> 10;
      int cc = col & 1023;
      int h = cc >> 6, d = cc & 63;
      for (int i = 0; i < 4; ++i) {
        int row = rowbase + i;
        int b = row >> 11, tt = row & 2047;
        size_t off = (((size_t)(b * 16 + h)) * 2048 + tt) * 64 + d;
        float v = acc[r][c][i];
        if (seg == 0)      Qh[off] = f2bf(v * qscale);
        else if (seg == 1) Kh[off] = f2bf(v);
        else               Vh[off] = f2bf(v);
      }
    }
  }
}

// ---- bf16 transpose: Vh[bh][2048][64] -> Vt[bh][64][2048], 64x64 LDS tiles ----
__global__ __launch_bounds__(256) void vT_kernel(const u16* __restrict__ Vh,
                                                 u16* __restrict__ Vt) {
  __shared__ __align__(16) u16 ls[64 * 72];
  int t = threadIdx.x;
  int t0 = blockIdx.x * 64, bh = blockIdx.y;
  const u16* in = Vh + ((size_t)bh * 2048 + t0) * 64;
  for (int u = t; u < 512; u += 256) {
    int row = u >> 3, col = (u & 7) << 3;
    *(u32x4*)&ls[row * 72 + col] = *(const u32x4*)&in[(size_t)row * 64 + col];
  }
  __syncthreads();
  for (int u = t; u < 512; u += 256) {
    int d = u >> 3, tc = (u & 7) << 3;
    union { u16 h[8]; u32x4 v; } pk;
    for (int j = 0; j < 8; ++j) pk.h[j] = ls[(tc + j) * 72 + d];
    *(u32x4*)&Vt[((size_t)bh * 64 + d) * 2048 + t0 + tc] = pk.v;
  }
}

// ---- proj GEMM: 64x64 tile, 4 waves (wave tile 32x32), grid 64x16=1024 blocks ----
__global__ __launch_bounds__(256) void proj_gemm_kernel(
    const u16* __restrict__ A, const u16* __restrict__ Bt,
    float* __restrict__ out, const float* __restrict__ bias) {
  constexpr int K = 1024;
  __shared__ __align__(16) u16 As[64 * 32];
  __shared__ __align__(16) u16 Bs[64 * 32];
  int t = threadIdx.x;
  int wave = t >> 6, lane = t & 63, quad = lane >> 4, l16 = lane & 15;
  int wm = (wave >> 1) << 5, wn = (wave & 1) << 5;  // 2x2 wave grid, wave tile 32x32
  int m0 = blockIdx.x * 64, n0 = blockIdx.y * 64;
  f32x4 acc[2][2] = {};
  int u0 = t;  // 256 units of 16B per matrix
  int ra0 = u0 >> 2, ca0 = ((u0 & 3) ^ ((u0 >> 3) & 3)) << 3;
  int swq = (quad ^ ((l16 >> 1) & 3)) << 3;
  for (int k0 = 0; k0 < K; k0 += 32) {
    gld_lds16(&A[(size_t)(m0 + ra0) * K + k0 + ca0], &As[u0 * 8]);
    gld_lds16(&Bt[(size_t)(n0 + ra0) * K + k0 + ca0], &Bs[u0 * 8]);
    __syncthreads();
    bf16x8 af[2], bfr[2];
    for (int r = 0; r < 2; ++r) af[r] = ld_bf8(&As[(wm + r * 16 + l16) * 32 + swq]);
    for (int c = 0; c < 2; ++c) bfr[c] = ld_bf8(&Bs[(wn + c * 16 + l16) * 32 + swq]);
    for (int r = 0; r < 2; ++r)
      for (int c = 0; c < 2; ++c)
        acc[r][c] = __builtin_amdgcn_mfma_f32_16x16x32_bf16(af[r], bfr[c], acc[r][c], 0, 0, 0);
    __syncthreads();
  }
  for (int r = 0; r < 2; ++r) {
    int rowbase = m0 + wm + r * 16 + quad * 4;
    for (int c = 0; c < 2; ++c) {
      int col = n0 + wn + c * 16 + l16;
      float bv = bias[col];
      for (int i = 0; i < 4; ++i)
        out[(size_t)(rowbase + i) * 1024 + col] = acc[r][c][i] + bv;
    }
  }
}

// ---- flash attention: BQ=BN=64, 4 waves x 16 q-rows, static-max exp2 softmax ----
__global__ __launch_bounds__(256) void flash_kernel(
    const u16* __restrict__ Qh, const u16* __restrict__ Kh, const u16* __restrict__ Vt,
    u16* __restrict__ yb) {
  constexpr int LDK = 72;
  __shared__ __align__(16) u16 Ks[64 * LDK];
  __shared__ __align__(16) u16 Vs[64 * LDK];
  __shared__ __align__(16) u16 Ps[64 * LDK];
  int t = threadIdx.x, wave = t >> 6, lane = t & 63, quad = lane >> 4, l16 = lane & 15;
  int qtile = 31 - blockIdx.x;  // long blocks first
  int bh = blockIdx.y;
  int q0 = qtile << 6;
  const u16* Qb = Qh + (size_t)bh * 2048 * 64;
  const u16* Kb = Kh + (size_t)bh * 2048 * 64;
  const u16* Vb = Vt + (size_t)bh * 64 * 2048;
  bf16x8 qa0, qa1;
  {
    int qrow = q0 + wave * 16 + l16;
    qa0 = ld_bf8(&Qb[(size_t)qrow * 64 + quad * 8]);
    qa1 = ld_bf8(&Qb[(size_t)qrow * 64 + 32 + quad * 8]);
  }
  bf16x8 onesf;  // B-frag: column n=0 all ones -> D[:,0] = rowsum
  {
    union { u16 h[8]; bf16x8 b; } o;
    u16 v = (l16 == 0) ? (u16)0x3F80 : (u16)0;
    for (int i = 0; i < 8; ++i) o.h[i] = v;
    onesf = o.b;
  }
  f32x4 oacc[4] = {};
  f32x4 lacc = {};
  int nkv = qtile + 1;
  int r1 = t >> 3, s1 = (t & 7) << 3, r2 = r1 + 32;
  u32x4 kreg0, kreg1, vreg0, vreg1;
  kreg0 = *(const u32x4*)&Kb[(size_t)r1 * 64 + s1];
  kreg1 = *(const u32x4*)&Kb[(size_t)r2 * 64 + s1];
  vreg0 = *(const u32x4*)&Vb[(size_t)r1 * 2048 + s1];
  vreg1 = *(const u32x4*)&Vb[(size_t)r2 * 2048 + s1];
  for (int j = 0; j < nkv; ++j) {
    __syncthreads();
    *(u32x4*)&Ks[r1 * LDK + s1] = kreg0;
    *(u32x4*)&Ks[r2 * LDK + s1] = kreg1;
    *(u32x4*)&Vs[r1 * LDK + s1] = vreg0;
    *(u32x4*)&Vs[r2 * LDK + s1] = vreg1;
    __syncthreads();
    if (j + 1 < nkv) {
      int kv0 = (j + 1) << 6;
      kreg0 = *(const u32x4*)&Kb[(size_t)(kv0 + r1) * 64 + s1];
      kreg1 = *(const u32x4*)&Kb[(size_t)(kv0 + r2) * 64 + s1];
      vreg0 = *(const u32x4*)&Vb[(size_t)r1 * 2048 + kv0 + s1];
      vreg1 = *(const u32x4*)&Vb[(size_t)r2 * 2048 + kv0 + s1];
    }
    f32x4 s[4];
    for (int c = 0; c < 4; ++c) {
      bf16x8 kb0 = ld_bf8(&Ks[(c * 16 + l16) * LDK + quad * 8]);
      bf16x8 kb1 = ld_bf8(&Ks[(c * 16 + l16) * LDK + 32 + quad * 8]);
      f32x4 z = {0.f, 0.f, 0.f, 0.f};
      z = __builtin_amdgcn_mfma_f32_16x16x32_bf16(qa0, kb0, z, 0, 0, 0);
      s[c] = __builtin_amdgcn_mfma_f32_16x16x32_bf16(qa1, kb1, z, 0, 0, 0);
    }
    bool diag = (j == nkv - 1);
    for (int c = 0; c < 4; ++c)
      for (int i = 0; i < 4; ++i) {
        float p = __builtin_amdgcn_exp2f(s[c][i]);
        if (diag && (c * 16 + l16 > wave * 16 + quad * 4 + i)) p = 0.f;
        Ps[(wave * 16 + quad * 4 + i) * LDK + c * 16 + l16] = f2bf(p);
      }
    bf16x8 pa0 = ld_bf8(&Ps[(wave * 16 + l16) * LDK + quad * 8]);
    bf16x8 pa1 = ld_bf8(&Ps[(wave * 16 + l16) * LDK + 32 + quad * 8]);
    lacc = __builtin_amdgcn_mfma_f32_16x16x32_bf16(pa0, onesf, lacc, 0, 0, 0);
    lacc = __builtin_amdgcn_mfma_f32_16x16x32_bf16(pa1, onesf, lacc, 0, 0, 0);
    for (int dt = 0; dt < 4; ++dt) {
      bf16x8 vb0 = ld_bf8(&Vs[(dt * 16 + l16) * LDK + quad * 8]);
      bf16x8 vb1 = ld_bf8(&Vs[(dt * 16 + l16) * LDK + 32 + quad * 8]);
      oacc[dt] = __builtin_amdgcn_mfma_f32_16x16x32_bf16(pa0, vb0, oacc[dt], 0, 0, 0);
      oacc[dt] = __builtin_amdgcn_mfma_f32_16x16x32_bf16(pa1, vb1, oacc[dt], 0, 0, 0);
    }
  }
  int b = bh >> 4, h = bh & 15;
  for (int i = 0; i < 4; ++i) {
    float l = __shfl(lacc[i], quad * 16);
    float inv = 1.0f / l;
    int qq = q0 + wave * 16 + quad * 4 + i;
    size_t rowoff = ((size_t)(b * 2048 + qq)) * 1024 + h * 64;
    for (int dt = 0; dt < 4; ++dt)
      yb[rowoff + dt * 16 + l16] = f2bf(oacc[dt][i] * inv);
  }
}

extern "C" void kernel_launch(void* const* d_in, const int* in_sizes, int n_in,
                              void* d_out, int out_size, void* d_ws, size_t ws_size,
                              hipStream_t stream) {
  const float* x     = (const float*)d_in[0];
  const float* Wkqv  = (const float*)d_in[1];
  const float* Wproj = (const float*)d_in[2];
  const float* bproj = (const float*)d_in[3];
  float* out = (float*)d_out;

  u16* ws     = (u16*)d_ws;                       // 48 MB total scratch
  u16* xb     = ws;                               // 4096x1024 bf16
  u16* wkqvT  = xb + (size_t)4096 * 1024;         // 3072x1024 (W_kqv^T)
  u16* wprojT = wkqvT + (size_t)3072 * 1024;      // 1024x1024 (W_proj^T)
  u16* Qh     = wprojT + (size_t)1024 * 1024;     // [32][2048][64], pre-scaled
  u16* Kh     = Qh + (size_t)32 * 2048 * 64;      // [32][2048][64]
  u16* Vt     = Kh + (size_t)32 * 2048 * 64;      // [32][64][2048]
  u16* yb     = Vt + (size_t)32 * 2048 * 64;      // 4096x1024 attn out; doubles as Vh
  u16* Vh     = yb;                               // [32][2048][64], dead once Vt built

  const float QSCALE = 0.18033688011112042f;  // (1/sqrt(64)) * log2(e)

  conv_x_kernel<<<2048, 256, 0, stream>>>(x, xb);
  convT_kernel<<<dim3(16, 48), 256, 0, stream>>>(Wkqv, wkqvT, 1024, 3072);
  convT_kernel<<<dim3(16, 16), 256, 0, stream>>>(Wproj, wprojT, 1024, 1024);
  qkv_gemm_kernel<<<dim3(32, 24), 512, 0, stream>>>(xb, wkqvT, Qh, Kh, Vh, QSCALE);
  vT_kernel<<<dim3(32, 32), 256, 0, stream>>>(Vh, Vt);
  flash_kernel<<<dim3(32, 32), 256, 0, stream>>>(Qh, Kh, Vt, yb);
  proj_gemm_kernel<<<dim3(64, 16), 256, 0, stream>>>(yb, wprojT, out, bproj);
}

// Round 4
// 191.387 us; speedup vs baseline: 1.5526x; 1.0642x over previous
//
#include <hip/hip_runtime.h>

// Causal MHA forward, B=2 T=2048 C=1024 H=16 hs=64, fp32 in/out, bf16 MFMA internally.
// R4: flash computes S^T (A=K,B=Q) so P stores are packed ds_write_b64 row-major and PV
// reads them back as contiguous A-frags (no scattered b16 / no ones-mfma); long q-tiles
// kv-split into 2 blocks (static-max softmax => partials combine by addition) + combine.

typedef unsigned short u16;
typedef unsigned int u32;
typedef __bf16 bf16x8 __attribute__((ext_vector_type(8)));
typedef float f32x4 __attribute__((ext_vector_type(4)));
typedef u32 u32x4 __attribute__((ext_vector_type(4)));
typedef u16 u16x4 __attribute__((ext_vector_type(4)));

__device__ __forceinline__ u16 f2bf(float f) {
  u32 u = __float_as_uint(f);
  u32 r = u + 0x7FFFu + ((u >> 16) & 1u);  // RNE, finite inputs only
  return (u16)(r >> 16);
}

__device__ __forceinline__ bf16x8 ld_bf8(const u16* p) {
  union { u32x4 u; bf16x8 b; } x;
  x.u = *(const u32x4*)p;
  return x.b;
}

__device__ __forceinline__ void gld_lds16(const u16* g, u16* l) {
  __builtin_amdgcn_global_load_lds(
      (const __attribute__((address_space(1))) u32*)g,
      (__attribute__((address_space(3))) u32*)l, 16, 0, 0);
}

// ---- fp32 -> bf16, 8 elements/thread ----
__global__ __launch_bounds__(256) void conv_x_kernel(const float* __restrict__ src,
                                                     u16* __restrict__ dst) {
  int idx = blockIdx.x * 256 + threadIdx.x;
  const float4* s4 = (const float4*)src;
  float4 a = s4[2 * idx], b = s4[2 * idx + 1];
  union { u16 h[8]; u32x4 v; } pk;
  pk.h[0] = f2bf(a.x); pk.h[1] = f2bf(a.y); pk.h[2] = f2bf(a.z); pk.h[3] = f2bf(a.w);
  pk.h[4] = f2bf(b.x); pk.h[5] = f2bf(b.y); pk.h[6] = f2bf(b.z); pk.h[7] = f2bf(b.w);
  *(u32x4*)&dst[(size_t)idx * 8] = pk.v;
}

// ---- fp32 (R x Cc) -> bf16 transposed (Cc x R), 64x64 LDS tiles ----
__global__ __launch_bounds__(256) void convT_kernel(const float* __restrict__ src,
                                                    u16* __restrict__ dst, int R, int Cc) {
  __shared__ float ls[64][65];
  int r0 = blockIdx.x * 64, c0 = blockIdx.y * 64;
  int t = threadIdx.x;
  for (int u = t; u < 1024; u += 256) {
    int r = u >> 4, cs = (u & 15) << 2;
    float4 v = *(const float4*)&src[(size_t)(r0 + r) * Cc + (c0 + cs)];
    ls[r][cs] = v.x; ls[r][cs + 1] = v.y; ls[r][cs + 2] = v.z; ls[r][cs + 3] = v.w;
  }
  __syncthreads();
  for (int u = t; u < 1024; u += 256) {
    int n = u >> 4, ks = (u & 15) << 2;
    u16x4 o;
    o.x = f2bf(ls[ks][n]); o.y = f2bf(ls[ks + 1][n]);
    o.z = f2bf(ls[ks + 2][n]); o.w = f2bf(ls[ks + 3][n]);
    *(u16x4*)&dst[(size_t)(c0 + n) * R + (r0 + ks)] = o;
  }
}

// ---- QKV GEMM: 128x128 tile, 8 waves (wave tile 32x64), BK=32, K=1024 ----
__global__ __launch_bounds__(512) void qkv_gemm_kernel(
    const u16* __restrict__ A, const u16* __restrict__ Bt,
    u16* __restrict__ Qh, u16* __restrict__ Kh, u16* __restrict__ Vh, float qscale) {
  constexpr int K = 1024;
  __shared__ __align__(16) u16 As[128 * 32];
  __shared__ __align__(16) u16 Bs[128 * 32];
  int t = threadIdx.x;
  int wave = t >> 6, lane = t & 63, quad = lane >> 4, l16 = lane & 15;
  int wm = (wave >> 1) << 5, wn = (wave & 1) << 6;
  int m0 = blockIdx.x * 128, n0 = blockIdx.y * 128;
  f32x4 acc[2][4] = {};
  int u0 = t;
  int ra0 = u0 >> 2, ca0 = ((u0 & 3) ^ ((u0 >> 3) & 3)) << 3;
  int swq = (quad ^ ((l16 >> 1) & 3)) << 3;
  for (int k0 = 0; k0 < K; k0 += 32) {
    gld_lds16(&A[(size_t)(m0 + ra0) * K + k0 + ca0], &As[u0 * 8]);
    gld_lds16(&Bt[(size_t)(n0 + ra0) * K + k0 + ca0], &Bs[u0 * 8]);
    __syncthreads();
    bf16x8 af[2], bfr[4];
    for (int r = 0; r < 2; ++r) af[r] = ld_bf8(&As[(wm + r * 16 + l16) * 32 + swq]);
    for (int c = 0; c < 4; ++c) bfr[c] = ld_bf8(&Bs[(wn + c * 16 + l16) * 32 + swq]);
    for (int r = 0; r < 2; ++r)
      for (int c = 0; c < 4; ++c)
        acc[r][c] = __builtin_amdgcn_mfma_f32_16x16x32_bf16(af[r], bfr[c], acc[r][c], 0, 0, 0);
    __syncthreads();
  }
  for (int r = 0; r < 2; ++r) {
    int rowbase = m0 + wm + r * 16 + quad * 4;
    for (int c = 0; c < 4; ++c) {
      int col = n0 + wn + c * 16 + l16;
      int seg = col >> 10;
      int cc = col & 1023;
      int h = cc >> 6, d = cc & 63;
      for (int i = 0; i < 4; ++i) {
        int row = rowbase + i;
        int b = row >> 11, tt = row & 2047;
        size_t off = (((size_t)(b * 16 + h)) * 2048 + tt) * 64 + d;
        float v = acc[r][c][i];
        if (seg == 0)      Qh[off] = f2bf(v * qscale);
        else if (seg == 1) Kh[off] = f2bf(v);
        else               Vh[off] = f2bf(v);
      }
    }
  }
}

// ---- bf16 transpose: Vh[bh][2048][64] -> Vt[bh][64][2048] ----
__global__ __launch_bounds__(256) void vT_kernel(const u16* __restrict__ Vh,
                                                 u16* __restrict__ Vt) {
  __shared__ __align__(16) u16 ls[64 * 72];
  int t = threadIdx.x;
  int t0 = blockIdx.x * 64, bh = blockIdx.y;
  const u16* in = Vh + ((size_t)bh * 2048 + t0) * 64;
  for (int u = t; u < 512; u += 256) {
    int row = u >> 3, col = (u & 7) << 3;
    *(u32x4*)&ls[row * 72 + col] = *(const u32x4*)&in[(size_t)row * 64 + col];
  }
  __syncthreads();
  for (int u = t; u < 512; u += 256) {
    int d = u >> 3, tc = (u & 7) << 3;
    union { u16 h[8]; u32x4 v; } pk;
    for (int j = 0; j < 8; ++j) pk.h[j] = ls[(tc + j) * 72 + d];
    *(u32x4*)&Vt[((size_t)bh * 64 + d) * 2048 + t0 + tc] = pk.v;
  }
}

// ---- proj GEMM: 64x64 tile, 4 waves, grid 64x16 ----
__global__ __launch_bounds__(256) void proj_gemm_kernel(
    const u16* __restrict__ A, const u16* __restrict__ Bt,
    float* __restrict__ out, const float* __restrict__ bias) {
  constexpr int K = 1024;
  __shared__ __align__(16) u16 As[64 * 32];
  __shared__ __align__(16) u16 Bs[64 * 32];
  int t = threadIdx.x;
  int wave = t >> 6, lane = t & 63, quad = lane >> 4, l16 = lane & 15;
  int wm = (wave >> 1) << 5, wn = (wave & 1) << 5;
  int m0 = blockIdx.x * 64, n0 = blockIdx.y * 64;
  f32x4 acc[2][2] = {};
  int u0 = t;
  int ra0 = u0 >> 2, ca0 = ((u0 & 3) ^ ((u0 >> 3) & 3)) << 3;
  int swq = (quad ^ ((l16 >> 1) & 3)) << 3;
  for (int k0 = 0; k0 < K; k0 += 32) {
    gld_lds16(&A[(size_t)(m0 + ra0) * K + k0 + ca0], &As[u0 * 8]);
    gld_lds16(&Bt[(size_t)(n0 + ra0) * K + k0 + ca0], &Bs[u0 * 8]);
    __syncthreads();
    bf16x8 af[2], bfr[2];
    for (int r = 0; r < 2; ++r) af[r] = ld_bf8(&As[(wm + r * 16 + l16) * 32 + swq]);
    for (int c = 0; c < 2; ++c) bfr[c] = ld_bf8(&Bs[(wn + c * 16 + l16) * 32 + swq]);
    for (int r = 0; r < 2; ++r)
      for (int c = 0; c < 2; ++c)
        acc[r][c] = __builtin_amdgcn_mfma_f32_16x16x32_bf16(af[r], bfr[c], acc[r][c], 0, 0, 0);
    __syncthreads();
  }
  for (int r = 0; r < 2; ++r) {
    int rowbase = m0 + wm + r * 16 + quad * 4;
    for (int c = 0; c < 2; ++c) {
      int col = n0 + wn + c * 16 + l16;
      float bv = bias[col];
      for (int i = 0; i < 4; ++i)
        out[(size_t)(rowbase + i) * 1024 + col] = acc[r][c][i] + bv;
    }
  }
}

// ---- flash attention (S^T form): BQ=64, 4 waves x 16 q-rows, static-max exp2 softmax ----
// Jobs: qtile 0..18 full-range; qtile 19..31 kv-split into 2 partial blocks (fp32 O + lsum
// to Opart; static max => partials add). 45 jobs per bh.
__global__ __launch_bounds__(256) void flash_kernel(
    const u16* __restrict__ Qh, const u16* __restrict__ Kh, const u16* __restrict__ Vt,
    u16* __restrict__ yb, float* __restrict__ Opart) {
  constexpr int LDK = 72;
  __shared__ __align__(16) u16 Ks[64 * LDK];
  __shared__ __align__(16) u16 Vs[64 * LDK];
  __shared__ __align__(16) u16 Ps[64 * LDK];
  int t = threadIdx.x, wave = t >> 6, lane = t & 63, quad = lane >> 4, l16 = lane & 15;
  int jx = blockIdx.x, bh = blockIdx.y;
  int qtile, kvs, kve, sidx = 0, half = 0;
  bool partial;
  if (jx < 19) {            // full-range jobs, longest first
    qtile = 18 - jx; kvs = 0; kve = qtile + 1; partial = false;
  } else {                  // split jobs, longest first
    sidx = (jx - 19) >> 1; half = (jx - 19) & 1;
    qtile = 31 - sidx;
    int nkv = qtile + 1, mid = nkv >> 1;
    kvs = half ? mid : 0; kve = half ? nkv : mid; partial = true;
  }
  int q0 = qtile << 6;
  const u16* Qb = Qh + (size_t)bh * 2048 * 64;
  const u16* Kb = Kh + (size_t)bh * 2048 * 64;
  const u16* Vb = Vt + (size_t)bh * 64 * 2048;
  bf16x8 qa0, qa1;  // B-operand now; same per-lane layout as A
  {
    int qrow = q0 + wave * 16 + l16;
    qa0 = ld_bf8(&Qb[(size_t)qrow * 64 + quad * 8]);
    qa1 = ld_bf8(&Qb[(size_t)qrow * 64 + 32 + quad * 8]);
  }
  f32x4 oacc[4] = {};
  float lsum = 0.f;
  int r1 = t >> 3, s1 = (t & 7) << 3, r2 = r1 + 32;
  u32x4 kreg0, kreg1, vreg0, vreg1;
  {
    int kv0 = kvs << 6;
    kreg0 = *(const u32x4*)&Kb[(size_t)(kv0 + r1) * 64 + s1];
    kreg1 = *(const u32x4*)&Kb[(size_t)(kv0 + r2) * 64 + s1];
    vreg0 = *(const u32x4*)&Vb[(size_t)r1 * 2048 + kv0 + s1];
    vreg1 = *(const u32x4*)&Vb[(size_t)r2 * 2048 + kv0 + s1];
  }
  for (int j = kvs; j < kve; ++j) {
    int kv0 = j << 6;
    __syncthreads();
    *(u32x4*)&Ks[r1 * LDK + s1] = kreg0;
    *(u32x4*)&Ks[r2 * LDK + s1] = kreg1;
    *(u32x4*)&Vs[r1 * LDK + s1] = vreg0;
    *(u32x4*)&Vs[r2 * LDK + s1] = vreg1;
    __syncthreads();
    if (j + 1 < kve) {
      int kn = (j + 1) << 6;
      kreg0 = *(const u32x4*)&Kb[(size_t)(kn + r1) * 64 + s1];
      kreg1 = *(const u32x4*)&Kb[(size_t)(kn + r2) * 64 + s1];
      vreg0 = *(const u32x4*)&Vb[(size_t)r1 * 2048 + kn + s1];
      vreg1 = *(const u32x4*)&Vb[(size_t)r2 * 2048 + kn + s1];
    }
    // S^T tiles: D[m=kv(16-strip c)][n=q(16 of wave)]; lane: kv=quad*4+reg, q=l16
    f32x4 s[4];
    for (int c = 0; c < 4; ++c) {
      bf16x8 kb0 = ld_bf8(&Ks[(c * 16 + l16) * LDK + quad * 8]);
      bf16x8 kb1 = ld_bf8(&Ks[(c * 16 + l16) * LDK + 32 + quad * 8]);
      f32x4 z = {0.f, 0.f, 0.f, 0.f};
      z = __builtin_amdgcn_mfma_f32_16x16x32_bf16(kb0, qa0, z, 0, 0, 0);
      s[c] = __builtin_amdgcn_mfma_f32_16x16x32_bf16(kb1, qa1, s[c] = z, 0, 0, 0);
    }
    bool diag = (j == qtile);
    int qg = q0 + wave * 16 + l16;
    for (int c = 0; c < 4; ++c) {
      union { u16 h[4]; u16x4 v; } pk;
      for (int i = 0; i < 4; ++i) {
        float p = __builtin_amdgcn_exp2f(s[c][i]);
        if (diag && (kv0 + c * 16 + quad * 4 + i > qg)) p = 0.f;
        lsum += p;
        pk.h[i] = f2bf(p);
      }
      // P row-major [q][kv]: row = wave*16+l16, cols c*16+quad*4..+3 -> packed b64
      *(u16x4*)&Ps[(wave * 16 + l16) * LDK + c * 16 + quad * 4] = pk.v;
    }
    bf16x8 pa0 = ld_bf8(&Ps[(wave * 16 + l16) * LDK + quad * 8]);        // A-frag, contiguous
    bf16x8 pa1 = ld_bf8(&Ps[(wave * 16 + l16) * LDK + 32 + quad * 8]);
    for (int dt = 0; dt < 4; ++dt) {
      bf16x8 vb0 = ld_bf8(&Vs[(dt * 16 + l16) * LDK + quad * 8]);
      bf16x8 vb1 = ld_bf8(&Vs[(dt * 16 + l16) * LDK + 32 + quad * 8]);
      oacc[dt] = __builtin_amdgcn_mfma_f32_16x16x32_bf16(pa0, vb0, oacc[dt], 0, 0, 0);
      oacc[dt] = __builtin_amdgcn_mfma_f32_16x16x32_bf16(pa1, vb1, oacc[dt], 0, 0, 0);
    }
  }
  // rowsum: lane holds partial for q=l16; reduce across the 4 quad-groups
  lsum += __shfl_xor(lsum, 16);
  lsum += __shfl_xor(lsum, 32);
  if (partial) {
    float* Op = Opart + ((size_t)(bh * 13 + sidx) * 2 + half) * 4160;
    for (int dt = 0; dt < 4; ++dt)
      for (int i = 0; i < 4; ++i)
        Op[(wave * 16 + quad * 4 + i) * 64 + dt * 16 + l16] = oacc[dt][i];
    if (quad == 0) Op[4096 + wave * 16 + l16] = lsum;
  } else {
    int b = bh >> 4, h = bh & 15;
    for (int i = 0; i < 4; ++i) {
      float inv = 1.0f / __shfl(lsum, quad * 4 + i);  // rowsum for q_local=quad*4+i
      int qq = q0 + wave * 16 + quad * 4 + i;
      size_t rowoff = ((size_t)(b * 2048 + qq)) * 1024 + h * 64;
      for (int dt = 0; dt < 4; ++dt)
        yb[rowoff + dt * 16 + l16] = f2bf(oacc[dt][i] * inv);
    }
  }
}

// ---- combine split halves: O = O0+O1, l = l0+l1, write normalized bf16 ----
__global__ __launch_bounds__(256) void combine_kernel(const float* __restrict__ Opart,
                                                      u16* __restrict__ yb) {
  int sidx = blockIdx.x, bh = blockIdx.y, t = threadIdx.x;
  int qtile = 31 - sidx;
  const float* A = Opart + (size_t)(bh * 13 + sidx) * 2 * 4160;
  const float* Bp = A + 4160;
  int q = t >> 2, d0 = (t & 3) << 4;
  float inv = 1.0f / (A[4096 + q] + Bp[4096 + q]);
  int b = bh >> 4, h = bh & 15;
  size_t off = ((size_t)(b * 2048 + (qtile << 6) + q)) * 1024 + h * 64 + d0;
  union { u16 h[16]; u32x4 v[2]; } pk;
  for (int k = 0; k < 16; ++k)
    pk.h[k] = f2bf((A[q * 64 + d0 + k] + Bp[q * 64 + d0 + k]) * inv);
  *(u32x4*)&yb[off] = pk.v[0];
  *(u32x4*)&yb[off + 8] = pk.v[1];
}

extern "C" void kernel_launch(void* const* d_in, const int* in_sizes, int n_in,
                              void* d_out, int out_size, void* d_ws, size_t ws_size,
                              hipStream_t stream) {
  const float* x     = (const float*)d_in[0];
  const float* Wkqv  = (const float*)d_in[1];
  const float* Wproj = (const float*)d_in[2];
  const float* bproj = (const float*)d_in[3];
  float* out = (float*)d_out;

  u16* ws     = (u16*)d_ws;                       // 48 MB total scratch
  u16* xb     = ws;                               // 4096x1024 bf16 (dead after qkv)
  u16* wkqvT  = xb + (size_t)4096 * 1024;         // 3072x1024 (dead after qkv)
  u16* wprojT = wkqvT + (size_t)3072 * 1024;      // 1024x1024 (W_proj^T)
  u16* Qh     = wprojT + (size_t)1024 * 1024;     // [32][2048][64], pre-scaled
  u16* Kh     = Qh + (size_t)32 * 2048 * 64;      // [32][2048][64]
  u16* Vt     = Kh + (size_t)32 * 2048 * 64;      // [32][64][2048]
  u16* yb     = Vt + (size_t)32 * 2048 * 64;      // 4096x1024 attn out; doubles as Vh
  u16* Vh     = yb;
  float* Opart = (float*)ws;  // aliases xb+wkqvT (13.84 MB < 14 MB), used after qkv only

  const float QSCALE = 0.18033688011112042f;  // (1/sqrt(64)) * log2(e)

  conv_x_kernel<<<2048, 256, 0, stream>>>(x, xb);
  convT_kernel<<<dim3(16, 48), 256, 0, stream>>>(Wkqv, wkqvT, 1024, 3072);
  convT_kernel<<<dim3(16, 16), 256, 0, stream>>>(Wproj, wprojT, 1024, 1024);
  qkv_gemm_kernel<<<dim3(32, 24), 512, 0, stream>>>(xb, wkqvT, Qh, Kh, Vh, QSCALE);
  vT_kernel<<<dim3(32, 32), 256, 0, stream>>>(Vh, Vt);
  flash_kernel<<<dim3(45, 32), 256, 0, stream>>>(Qh, Kh, Vt, yb, Opart);
  combine_kernel<<<dim3(13, 32), 256, 0, stream>>>(Opart, yb);
  proj_gemm_kernel<<<dim3(64, 16), 256, 0, stream>>>(yb, wprojT, out, bproj);
}